// Round 1
// baseline (3889.430 us; speedup 1.0000x reference)
//
#include <hip/hip_runtime.h>
#include <hip/hip_bf16.h>
#include <cstddef>

// Problem constants (fixed by reference)
#define BATCH   2
#define S_LEN   2048
#define D_MODEL 1024
#define NH      16
#define HD      64
#define MAXD    1024

// logits = scores*(1/sqrt(64)) + (scores + rel_bias)*64^-0.25
//        = scores*0.47855339 + rel_bias*0.35355339
#define SCORE_SCALE 0.47855339059327373f
#define BIAS_SCALE  0.35355339059327373f

// ---------------------------------------------------------------------------
// Tiled fp32 GEMM: C[M,N] = A[M,K] @ B[K,N] (+ bias[N]) ; row-major everywhere
// 64x64 block tile, BK=16, 256 threads, 4x4 micro-tile per thread.
// ---------------------------------------------------------------------------
#define BM 64
#define BN 64
#define BK 16

__global__ __launch_bounds__(256) void gemm_bias(
    const float* __restrict__ A, const float* __restrict__ B,
    const float* __restrict__ bias, float* __restrict__ C,
    int M, int N, int K)
{
    __shared__ float As[BK][BM + 1];  // transposed A tile, +1 pad kills store conflicts
    __shared__ float Bs[BK][BN];

    const int tid = threadIdx.x;
    const int bm = blockIdx.y * BM;
    const int bn = blockIdx.x * BN;
    const int tx = tid & 15;        // 16 col-groups
    const int ty = tid >> 4;        // 16 row-groups

    // global->LDS load mapping
    const int am = tid >> 2;              // A row within tile (0..63)
    const int ak = (tid & 3) * 4;         // A col group (0..12)
    const int bk = tid >> 4;              // B row within tile (0..15)
    const int bn0 = (tid & 15) * 4;       // B col group

    float acc[4][4] = {};

    for (int k0 = 0; k0 < K; k0 += BK) {
        const float4 a4 = *(const float4*)&A[(size_t)(bm + am) * K + k0 + ak];
        const float4 b4 = *(const float4*)&B[(size_t)(k0 + bk) * N + bn + bn0];
        __syncthreads();   // previous tile's compute done before overwrite
        As[ak + 0][am] = a4.x;
        As[ak + 1][am] = a4.y;
        As[ak + 2][am] = a4.z;
        As[ak + 3][am] = a4.w;
        *(float4*)&Bs[bk][bn0] = b4;
        __syncthreads();

        #pragma unroll
        for (int kk = 0; kk < BK; kk++) {
            float av[4], bv[4];
            #pragma unroll
            for (int i = 0; i < 4; i++) av[i] = As[kk][ty * 4 + i];
            #pragma unroll
            for (int j = 0; j < 4; j++) bv[j] = Bs[kk][tx * 4 + j];
            #pragma unroll
            for (int i = 0; i < 4; i++)
                #pragma unroll
                for (int j = 0; j < 4; j++)
                    acc[i][j] += av[i] * bv[j];
        }
    }

    float4 bias4 = make_float4(0.f, 0.f, 0.f, 0.f);
    if (bias) bias4 = *(const float4*)&bias[bn + tx * 4];

    #pragma unroll
    for (int i = 0; i < 4; i++) {
        const size_t row = bm + ty * 4 + i;
        float4 r;
        r.x = acc[i][0] + bias4.x;
        r.y = acc[i][1] + bias4.y;
        r.z = acc[i][2] + bias4.z;
        r.w = acc[i][3] + bias4.w;
        *(float4*)&C[row * N + bn + tx * 4] = r;
    }
}

// ---------------------------------------------------------------------------
// Flash-style attention, fp32.
// Grid: (S/TQ, H, B). Block: 256 threads. Q/K/V in [B,S,D] layout (head at h*64).
// Each block: TQ=32 query rows, streams K/V in TK=32 tiles, online softmax.
// ---------------------------------------------------------------------------
#define TQ 32
#define TK 32
#define KPAD 68   // 64+4: keeps float4 alignment, reduces bank conflicts

__global__ __launch_bounds__(256) void attn_kernel(
    const float* __restrict__ Q, const float* __restrict__ K,
    const float* __restrict__ V, const float* __restrict__ pos_bias,
    float* __restrict__ O)
{
    const int qt = blockIdx.x;
    const int h  = blockIdx.y;
    const int b  = blockIdx.z;
    const int tid = threadIdx.x;
    const int qbase = qt * TQ;

    __shared__ float Qs[TQ][HD];
    __shared__ float Ks[TK][KPAD];
    __shared__ float Vs[TK][KPAD];
    __shared__ float Ps[TQ][TK + 1];
    __shared__ float mrow[TQ], lrow[TQ], arow[TQ];

    const int lr = tid >> 3;          // tile row for loads (0..31)
    const int lc = (tid & 7) * 8;     // 8 consecutive cols

    // load Q tile
    {
        const float* src = &Q[((size_t)b * S_LEN + qbase + lr) * D_MODEL + h * HD + lc];
        *(float4*)&Qs[lr][lc]     = *(const float4*)src;
        *(float4*)&Qs[lr][lc + 4] = *(const float4*)(src + 4);
    }
    if (tid < TQ) { mrow[tid] = -1e30f; lrow[tid] = 0.f; }

    const int qr = tid >> 3;          // query row this thread works on (0..31)
    const int kg = (tid & 7) * 4;     // 4 key cols for score phase
    const int cg = (tid & 7) * 8;     // 8 output cols for PV phase
    const int qi = qbase + qr;

    float o[8] = {0.f, 0.f, 0.f, 0.f, 0.f, 0.f, 0.f, 0.f};

    for (int kb = 0; kb < S_LEN; kb += TK) {
        __syncthreads();  // prev PV done before K/V overwrite
        {
            const float* ks = &K[((size_t)b * S_LEN + kb + lr) * D_MODEL + h * HD + lc];
            const float* vs = &V[((size_t)b * S_LEN + kb + lr) * D_MODEL + h * HD + lc];
            *(float4*)&Ks[lr][lc]     = *(const float4*)ks;
            *(float4*)&Ks[lr][lc + 4] = *(const float4*)(ks + 4);
            *(float4*)&Vs[lr][lc]     = *(const float4*)vs;
            *(float4*)&Vs[lr][lc + 4] = *(const float4*)(vs + 4);
        }
        __syncthreads();

        // score phase: 4 dots per thread
        #pragma unroll
        for (int j = 0; j < 4; j++) {
            const int kc = kg + j;
            float acc = 0.f;
            #pragma unroll
            for (int d = 0; d < HD; d++)
                acc += Qs[qr][d] * Ks[kc][d];
            const int kj = kb + kc;
            int rel = qi - kj;
            rel = min(max(rel, -(MAXD - 1)), MAXD - 1);
            const float bias = pos_bias[(size_t)(rel + MAXD - 1) * NH + h];
            Ps[qr][kc] = acc * SCORE_SCALE + bias * BIAS_SCALE;
        }
        __syncthreads();

        // online softmax update (one thread per row)
        if (tid < TQ) {
            const int r = tid;
            const float m_old = mrow[r];
            float mx = m_old;
            for (int j = 0; j < TK; j++) mx = fmaxf(mx, Ps[r][j]);
            const float alpha = __expf(m_old - mx);
            float sum = 0.f;
            for (int j = 0; j < TK; j++) {
                const float p = __expf(Ps[r][j] - mx);
                Ps[r][j] = p;
                sum += p;
            }
            mrow[r] = mx;
            lrow[r] = lrow[r] * alpha + sum;
            arow[r] = alpha;
        }
        __syncthreads();

        // PV accumulation
        const float alpha = arow[qr];
        #pragma unroll
        for (int c = 0; c < 8; c++) o[c] *= alpha;
        #pragma unroll
        for (int j = 0; j < TK; j++) {
            const float p = Ps[qr][j];
            #pragma unroll
            for (int c = 0; c < 8; c++)
                o[c] += p * Vs[j][cg + c];
        }
    }

    const float inv = 1.0f / lrow[qr];
    float* dst = &O[((size_t)b * S_LEN + qi) * D_MODEL + h * HD + cg];
    float4 r0, r1;
    r0.x = o[0] * inv; r0.y = o[1] * inv; r0.z = o[2] * inv; r0.w = o[3] * inv;
    r1.x = o[4] * inv; r1.y = o[5] * inv; r1.z = o[6] * inv; r1.w = o[7] * inv;
    *(float4*)dst       = r0;
    *(float4*)(dst + 4) = r1;
}

// ---------------------------------------------------------------------------
extern "C" void kernel_launch(void* const* d_in, const int* in_sizes, int n_in,
                              void* d_out, int out_size, void* d_ws, size_t ws_size,
                              hipStream_t stream)
{
    const float* x        = (const float*)d_in[0];
    const float* Wq       = (const float*)d_in[1];
    const float* bq       = (const float*)d_in[2];
    const float* Wk       = (const float*)d_in[3];
    const float* Wv       = (const float*)d_in[4];
    const float* bv       = (const float*)d_in[5];
    const float* Wo       = (const float*)d_in[6];
    const float* bo       = (const float*)d_in[7];
    const float* pos_bias = (const float*)d_in[8];
    float* out = (float*)d_out;

    const size_t ELEMS = (size_t)BATCH * S_LEN * D_MODEL;  // 8 M floats
    float* Qb = (float*)d_ws;
    float* Kb = Qb + ELEMS;
    float* Vb = Kb + ELEMS;
    float* Ab = Vb + ELEMS;   // attention output, pre-projection

    const int M = BATCH * S_LEN;  // 4096
    dim3 gemm_grid(D_MODEL / BN, M / BM);  // (16, 64)

    gemm_bias<<<gemm_grid, 256, 0, stream>>>(x, Wq, bq,      Qb, M, D_MODEL, D_MODEL);
    gemm_bias<<<gemm_grid, 256, 0, stream>>>(x, Wk, nullptr, Kb, M, D_MODEL, D_MODEL);
    gemm_bias<<<gemm_grid, 256, 0, stream>>>(x, Wv, bv,      Vb, M, D_MODEL, D_MODEL);

    attn_kernel<<<dim3(S_LEN / TQ, NH, BATCH), 256, 0, stream>>>(Qb, Kb, Vb, pos_bias, Ab);

    gemm_bias<<<gemm_grid, 256, 0, stream>>>(Ab, Wo, bo, out, M, D_MODEL, D_MODEL);
}

// Round 2
// 724.194 us; speedup vs baseline: 5.3707x; 5.3707x over previous
//
#include <hip/hip_runtime.h>
#include <hip/hip_bf16.h>
#include <cstddef>

// Problem constants (fixed by reference)
#define BATCH   2
#define S_LEN   2048
#define D_MODEL 1024
#define NH      16
#define HD      64
#define MAXD    1024

// logits = scores*(1/sqrt(64)) + (scores + rel_bias)*64^-0.25
//        = scores*0.47855339 + rel_bias*0.35355339
#define SCORE_SCALE 0.47855339059327373f
#define BIAS_SCALE  0.35355339059327373f

typedef __attribute__((ext_vector_type(8))) short bf16x8;
typedef __attribute__((ext_vector_type(4))) float f32x4;

static __device__ __forceinline__ unsigned short f2bf(float f) {
    __hip_bfloat16 h = __float2bfloat16(f);
    return *reinterpret_cast<unsigned short*>(&h);
}

// ---------------------------------------------------------------------------
// Tiled fp32 GEMM: C[M,N] = A[M,K] @ B[K,N] (+ bias[N]); optional bf16 output.
// 64x64 tile, BK=16, 256 threads, 4x4 micro-tile.
// ---------------------------------------------------------------------------
#define BM 64
#define BN 64
#define BK 16

template<bool BF16OUT>
__global__ __launch_bounds__(256) void gemm_bias(
    const float* __restrict__ A, const float* __restrict__ B,
    const float* __restrict__ bias, void* __restrict__ Cout,
    int M, int N, int K)
{
    __shared__ float As[BK][BM + 1];
    __shared__ float Bs[BK][BN];

    const int tid = threadIdx.x;
    const int bm = blockIdx.y * BM;
    const int bn = blockIdx.x * BN;
    const int tx = tid & 15;
    const int ty = tid >> 4;

    const int am = tid >> 2;
    const int ak = (tid & 3) * 4;
    const int bk = tid >> 4;
    const int bn0 = (tid & 15) * 4;

    float acc[4][4] = {};

    for (int k0 = 0; k0 < K; k0 += BK) {
        const float4 a4 = *(const float4*)&A[(size_t)(bm + am) * K + k0 + ak];
        const float4 b4 = *(const float4*)&B[(size_t)(k0 + bk) * N + bn + bn0];
        __syncthreads();
        As[ak + 0][am] = a4.x;
        As[ak + 1][am] = a4.y;
        As[ak + 2][am] = a4.z;
        As[ak + 3][am] = a4.w;
        *(float4*)&Bs[bk][bn0] = b4;
        __syncthreads();

        #pragma unroll
        for (int kk = 0; kk < BK; kk++) {
            float av[4], bv[4];
            #pragma unroll
            for (int i = 0; i < 4; i++) av[i] = As[kk][ty * 4 + i];
            #pragma unroll
            for (int j = 0; j < 4; j++) bv[j] = Bs[kk][tx * 4 + j];
            #pragma unroll
            for (int i = 0; i < 4; i++)
                #pragma unroll
                for (int j = 0; j < 4; j++)
                    acc[i][j] += av[i] * bv[j];
        }
    }

    float4 bias4 = make_float4(0.f, 0.f, 0.f, 0.f);
    if (bias) bias4 = *(const float4*)&bias[bn + tx * 4];
    const float bb[4] = {bias4.x, bias4.y, bias4.z, bias4.w};

    #pragma unroll
    for (int i = 0; i < 4; i++) {
        const size_t row = bm + ty * 4 + i;
        if (BF16OUT) {
            unsigned short* C = (unsigned short*)Cout;
            #pragma unroll
            for (int j = 0; j < 4; j++)
                C[row * N + bn + tx * 4 + j] = f2bf(acc[i][j] + bb[j]);
        } else {
            float* C = (float*)Cout;
            float4 r;
            r.x = acc[i][0] + bb[0];
            r.y = acc[i][1] + bb[1];
            r.z = acc[i][2] + bb[2];
            r.w = acc[i][3] + bb[3];
            *(float4*)&C[row * N + bn + tx * 4] = r;
        }
    }
}

// ---------------------------------------------------------------------------
// MFMA flash attention (bf16 inputs, fp32 accum/output).
// Grid (S/64, NH, BATCH), 256 threads = 4 waves; each wave owns 16 q-rows.
// K-tiles of 64 keys streamed through LDS; V stored transposed [d][key].
// Online softmax in-register via shfl over 16-lane quad groups.
// ---------------------------------------------------------------------------
#define TQB 64
#define TKB 64
#define KP  72   // padded inner stride (bf16 elems): 144 B rows -> 2-way max

__global__ __launch_bounds__(256) void attn_mfma(
    const unsigned short* __restrict__ Q, const unsigned short* __restrict__ K,
    const unsigned short* __restrict__ V, const float* __restrict__ pos_bias,
    float* __restrict__ O)
{
    const int qt = blockIdx.x, h = blockIdx.y, b = blockIdx.z;
    const int tid  = threadIdx.x;
    const int wave = tid >> 6, lane = tid & 63;
    const int quad = lane >> 4, col = lane & 15;
    const int qbase = qt * TQB;
    const int qw = qbase + wave * 16;

    __shared__ __align__(16) unsigned short Ks[TKB][KP];   // [key][d]
    __shared__ __align__(16) unsigned short Vt[HD][KP];    // [d][key]
    __shared__ __align__(16) unsigned short Ps[4][16][KP]; // per-wave P
    __shared__ float bias_s[128];

    // Q fragments (fixed for whole kernel): A-layout m=col, k=quad*8+j (+32 for kk=1)
    bf16x8 qf[2];
    {
        const unsigned short* qp =
            &Q[((size_t)(b * S_LEN) + qw + col) * D_MODEL + h * HD + quad * 8];
        qf[0] = *(const bf16x8*)qp;
        qf[1] = *(const bf16x8*)(qp + 32);
    }

    f32x4 accO[4];
    float m_i[4], l_i[4];
    #pragma unroll
    for (int r = 0; r < 4; r++) {
        m_i[r] = -1e30f; l_i[r] = 0.f;
        #pragma unroll
        for (int nb = 0; nb < 4; nb++) accO[nb][r] = 0.f;
    }

    const int skey = tid & 63;
    const int sd   = (tid >> 6) * 16;

    for (int kb = 0; kb < S_LEN; kb += TKB) {
        __syncthreads();  // prior tile's LDS reads complete
        {
            const size_t rowbase = ((size_t)(b * S_LEN) + kb + skey) * D_MODEL + h * HD + sd;
            const uint4 k0 = *(const uint4*)&K[rowbase];
            const uint4 k1 = *(const uint4*)&K[rowbase + 8];
            const uint4 v0 = *(const uint4*)&V[rowbase];
            const uint4 v1 = *(const uint4*)&V[rowbase + 8];
            *(uint4*)&Ks[skey][sd]     = k0;
            *(uint4*)&Ks[skey][sd + 8] = k1;
            unsigned short tmp[16];
            *(uint4*)&tmp[0] = v0;
            *(uint4*)&tmp[8] = v1;
            #pragma unroll
            for (int i = 0; i < 16; i++) Vt[sd + i][skey] = tmp[i];  // transpose
        }
        if (tid < 127) {
            int rel = qbase - kb + tid - 63;
            rel = min(max(rel, -(MAXD - 1)), MAXD - 1);
            bias_s[tid] = BIAS_SCALE * pos_bias[(size_t)(rel + MAXD - 1) * NH + h];
        }
        __syncthreads();

        // QK^T: C[q=quad*4+r][key=nb*16+col]
        f32x4 accS[4];
        #pragma unroll
        for (int nb = 0; nb < 4; nb++)
            #pragma unroll
            for (int r = 0; r < 4; r++) accS[nb][r] = 0.f;
        #pragma unroll
        for (int kk = 0; kk < 2; kk++)
            #pragma unroll
            for (int nb = 0; nb < 4; nb++) {
                const bf16x8 kf = *(const bf16x8*)&Ks[nb * 16 + col][kk * 32 + quad * 8];
                accS[nb] = __builtin_amdgcn_mfma_f32_16x16x32_bf16(qf[kk], kf, accS[nb], 0, 0, 0);
            }

        // online softmax (rows live in 16-lane quad groups)
        float pf[4][4];  // [nb][r]
        #pragma unroll
        for (int r = 0; r < 4; r++) {
            const int qoff = wave * 16 + quad * 4 + r + 63;
            float lg[4];
            float mx = -1e30f;
            #pragma unroll
            for (int nb = 0; nb < 4; nb++) {
                lg[nb] = accS[nb][r] * SCORE_SCALE + bias_s[qoff - nb * 16 - col];
                mx = fmaxf(mx, lg[nb]);
            }
            #pragma unroll
            for (int s = 1; s < 16; s <<= 1) mx = fmaxf(mx, __shfl_xor(mx, s));
            const float mnew  = fmaxf(m_i[r], mx);
            const float alpha = __expf(m_i[r] - mnew);
            m_i[r] = mnew;
            float sum = 0.f;
            #pragma unroll
            for (int nb = 0; nb < 4; nb++) {
                const float p = __expf(lg[nb] - mnew);
                pf[nb][r] = p;
                sum += p;
            }
            #pragma unroll
            for (int s = 1; s < 16; s <<= 1) sum += __shfl_xor(sum, s);
            l_i[r] = l_i[r] * alpha + sum;
            #pragma unroll
            for (int nb = 0; nb < 4; nb++) accO[nb][r] *= alpha;
        }

        // P: C-layout -> LDS -> A-layout (wave-private, no barrier needed)
        #pragma unroll
        for (int nb = 0; nb < 4; nb++)
            #pragma unroll
            for (int r = 0; r < 4; r++)
                Ps[wave][quad * 4 + r][nb * 16 + col] = f2bf(pf[nb][r]);

        // PV: O[q][d=nb*16+col] += P[q][key] * V[key][d]
        #pragma unroll
        for (int kk = 0; kk < 2; kk++) {
            const bf16x8 af = *(const bf16x8*)&Ps[wave][col][kk * 32 + quad * 8];
            #pragma unroll
            for (int nb = 0; nb < 4; nb++) {
                const bf16x8 vf = *(const bf16x8*)&Vt[nb * 16 + col][kk * 32 + quad * 8];
                accO[nb] = __builtin_amdgcn_mfma_f32_16x16x32_bf16(af, vf, accO[nb], 0, 0, 0);
            }
        }
    }

    // epilogue: divide by l, store fp32
    #pragma unroll
    for (int r = 0; r < 4; r++) {
        const float inv = 1.0f / l_i[r];
        const size_t row = (size_t)(b * S_LEN) + qw + quad * 4 + r;
        #pragma unroll
        for (int nb = 0; nb < 4; nb++)
            O[row * D_MODEL + h * HD + nb * 16 + col] = accO[nb][r] * inv;
    }
}

// ---------------------------------------------------------------------------
extern "C" void kernel_launch(void* const* d_in, const int* in_sizes, int n_in,
                              void* d_out, int out_size, void* d_ws, size_t ws_size,
                              hipStream_t stream)
{
    const float* x        = (const float*)d_in[0];
    const float* Wq       = (const float*)d_in[1];
    const float* bq       = (const float*)d_in[2];
    const float* Wk       = (const float*)d_in[3];
    const float* Wv       = (const float*)d_in[4];
    const float* bv       = (const float*)d_in[5];
    const float* Wo       = (const float*)d_in[6];
    const float* bo       = (const float*)d_in[7];
    const float* pos_bias = (const float*)d_in[8];
    float* out = (float*)d_out;

    const size_t ELEMS = (size_t)BATCH * S_LEN * D_MODEL;  // 8 Mi
    unsigned short* Qb = (unsigned short*)d_ws;             // bf16
    unsigned short* Kb = Qb + ELEMS;
    unsigned short* Vb = Kb + ELEMS;
    float* Ab = (float*)(Vb + ELEMS);                       // fp32 attn out

    const int M = BATCH * S_LEN;  // 4096
    dim3 gemm_grid(D_MODEL / BN, M / BM);

    gemm_bias<true ><<<gemm_grid, 256, 0, stream>>>(x, Wq, bq,      Qb, M, D_MODEL, D_MODEL);
    gemm_bias<true ><<<gemm_grid, 256, 0, stream>>>(x, Wk, nullptr, Kb, M, D_MODEL, D_MODEL);
    gemm_bias<true ><<<gemm_grid, 256, 0, stream>>>(x, Wv, bv,      Vb, M, D_MODEL, D_MODEL);

    attn_mfma<<<dim3(S_LEN / TQB, NH, BATCH), 256, 0, stream>>>(Qb, Kb, Vb, pos_bias, Ab);

    gemm_bias<false><<<gemm_grid, 256, 0, stream>>>(Ab, Wo, bo, out, M, D_MODEL, D_MODEL);
}

// Round 3
// 306.045 us; speedup vs baseline: 12.7087x; 2.3663x over previous
//
#include <hip/hip_runtime.h>
#include <hip/hip_bf16.h>
#include <cstddef>
#include <cstdint>

// Problem constants (fixed by reference)
#define BATCH   2
#define S_LEN   2048
#define D_MODEL 1024
#define NH      16
#define HD      64
#define MAXD    1024

// logits = scores*(1/sqrt(64)) + (scores + rel_bias)*64^-0.25
//        = scores*0.47855339 + rel_bias*0.35355339
#define SCORE_SCALE 0.47855339059327373f
#define BIAS_SCALE  0.35355339059327373f
// fixed softmax shift: |logit| << 88, softmax is shift-invariant, divide by l at end
#define FIXM 8.0f

typedef __attribute__((ext_vector_type(8))) short bf16x8;
typedef __attribute__((ext_vector_type(4))) float f32x4;

static __device__ __forceinline__ unsigned short f2bf(float f) {
    __hip_bfloat16 h = __float2bfloat16(f);
    return *reinterpret_cast<unsigned short*>(&h);
}
static __device__ __forceinline__ float bf2f(unsigned short u) {
    union { unsigned int i; float f; } c;
    c.i = ((unsigned int)u) << 16;
    return c.f;
}

#define GLDS(gp, lp) __builtin_amdgcn_global_load_lds( \
    (const __attribute__((address_space(1))) void*)(gp), \
    (__attribute__((address_space(3))) void*)(lp), 16, 0, 0)

// ---------------------------------------------------------------------------
// fp32 -> bf16 elementwise convert (x). n must be divisible by 2048*8.
// ---------------------------------------------------------------------------
__global__ __launch_bounds__(256) void cvt_bf16(
    const float* __restrict__ src, unsigned short* __restrict__ dst)
{
    const size_t i = ((size_t)blockIdx.x * 256 + threadIdx.x) * 8;
    const float4 a = *(const float4*)(src + i);
    const float4 b = *(const float4*)(src + i + 4);
    unsigned short u[8] = {f2bf(a.x), f2bf(a.y), f2bf(a.z), f2bf(a.w),
                           f2bf(b.x), f2bf(b.y), f2bf(b.z), f2bf(b.w)};
    *(uint4*)(dst + i) = *(const uint4*)u;
}

// ---------------------------------------------------------------------------
// Weight transpose+convert: W fp32 [K=1024][N=1024] -> Wt bf16 [N][K],
// optional low-residual part (split precision). Grid (32,32), 256 thr.
// ---------------------------------------------------------------------------
__global__ __launch_bounds__(256) void wt_convert(
    const float* __restrict__ W, unsigned short* __restrict__ hi,
    unsigned short* __restrict__ lo)
{
    __shared__ float t[32][33];
    const int bx = blockIdx.x * 32, by = blockIdx.y * 32;
    const int tx = threadIdx.x & 31, ty = threadIdx.x >> 5;  // ty 0..7
    #pragma unroll
    for (int i = 0; i < 4; i++)
        t[ty + 8 * i][tx] = W[(size_t)(by + ty + 8 * i) * 1024 + bx + tx];
    __syncthreads();
    #pragma unroll
    for (int i = 0; i < 4; i++) {
        const float v = t[tx][ty + 8 * i];       // = W[by+tx][bx+ty+8i]
        const unsigned short h = f2bf(v);
        const size_t o = (size_t)(bx + ty + 8 * i) * 1024 + by + tx;
        hi[o] = h;
        if (lo) lo[o] = f2bf(v - bf2f(h));
    }
}

// ---------------------------------------------------------------------------
// bf16 MFMA GEMM: C[M,N] = A[M,K] @ Bt[N,K]^T (+bias).
// 128x128 tile, BK=32, 256 threads = 4 waves (2x2), 4x4 16x16x32 frags/wave.
// global_load_lds width-16 staging (m97 structure).
// MODE 0: bf16 C [M,N].  MODE 1: bf16 V^T [b][h][d][s].  MODE 2: fp32 C.
// SPLITB: accumulate A@Bt + A@Bt2 (split-precision weight).
// ---------------------------------------------------------------------------
#define GBM 128
#define GBN 128
#define GBK 32

template<int MODE, bool SPLITB>
__global__ __launch_bounds__(256) void gemm_mfma(
    const unsigned short* __restrict__ A, const unsigned short* __restrict__ Bt,
    const unsigned short* __restrict__ Bt2, const float* __restrict__ bias,
    void* __restrict__ Cout, int M, int N, int K)
{
    __shared__ __align__(16) unsigned short As[GBM][GBK];
    __shared__ __align__(16) unsigned short Bs[SPLITB ? 2 : 1][GBN][GBK];

    const int tid = threadIdx.x;
    const int wave = tid >> 6, lane = tid & 63;
    const int quad = lane >> 4, cl = lane & 15;
    const int wm = (wave & 1) * 64, wn = (wave >> 1) * 64;
    const int bm = blockIdx.y * GBM, bn = blockIdx.x * GBN;

    // staging: wave w covers rows [w*32, w*32+32) of each 128x32 tile,
    // via two glds instructions (16 rows = 1024 B each).
    const int sr = wave * 32 + (lane >> 2);   // row for instr 0 (instr 1: +16)
    const int sc = (lane & 3) * 8;            // elem offset (16 B chunk)
    const unsigned short* aS0 = A   + (size_t)(bm + sr) * K + sc;
    const unsigned short* aS1 = aS0 + (size_t)16 * K;
    const unsigned short* bS0 = Bt  + (size_t)(bn + sr) * K + sc;
    const unsigned short* bS1 = bS0 + (size_t)16 * K;
    const unsigned short* cS0 = SPLITB ? Bt2 + (size_t)(bn + sr) * K + sc : nullptr;
    const unsigned short* cS1 = SPLITB ? cS0 + (size_t)16 * K : nullptr;
    unsigned short* aD0 = &As[wave * 32][0];
    unsigned short* aD1 = &As[wave * 32 + 16][0];
    unsigned short* bD0 = &Bs[0][wave * 32][0];
    unsigned short* bD1 = &Bs[0][wave * 32 + 16][0];
    unsigned short* cD0 = SPLITB ? &Bs[1][wave * 32][0] : nullptr;
    unsigned short* cD1 = SPLITB ? &Bs[1][wave * 32 + 16][0] : nullptr;

    f32x4 acc[4][4];
    #pragma unroll
    for (int mi = 0; mi < 4; mi++)
        #pragma unroll
        for (int ni = 0; ni < 4; ni++)
            #pragma unroll
            for (int r = 0; r < 4; r++) acc[mi][ni][r] = 0.f;

    for (int k0 = 0; k0 < K; k0 += GBK) {
        __syncthreads();
        GLDS(aS0, aD0); GLDS(aS1, aD1);
        GLDS(bS0, bD0); GLDS(bS1, bD1);
        if (SPLITB) { GLDS(cS0, cD0); GLDS(cS1, cD1); }
        aS0 += GBK; aS1 += GBK; bS0 += GBK; bS1 += GBK;
        if (SPLITB) { cS0 += GBK; cS1 += GBK; }
        __syncthreads();  // barrier drains vmcnt -> glds data visible

        bf16x8 af[4], bf[4];
        #pragma unroll
        for (int mi = 0; mi < 4; mi++)
            af[mi] = *(const bf16x8*)&As[wm + mi * 16 + cl][quad * 8];
        #pragma unroll
        for (int ni = 0; ni < 4; ni++)
            bf[ni] = *(const bf16x8*)&Bs[0][wn + ni * 16 + cl][quad * 8];
        #pragma unroll
        for (int mi = 0; mi < 4; mi++)
            #pragma unroll
            for (int ni = 0; ni < 4; ni++)
                acc[mi][ni] = __builtin_amdgcn_mfma_f32_16x16x32_bf16(
                    af[mi], bf[ni], acc[mi][ni], 0, 0, 0);
        if (SPLITB) {
            bf16x8 bf2[4];
            #pragma unroll
            for (int ni = 0; ni < 4; ni++)
                bf2[ni] = *(const bf16x8*)&Bs[1][wn + ni * 16 + cl][quad * 8];
            #pragma unroll
            for (int mi = 0; mi < 4; mi++)
                #pragma unroll
                for (int ni = 0; ni < 4; ni++)
                    acc[mi][ni] = __builtin_amdgcn_mfma_f32_16x16x32_bf16(
                        af[mi], bf2[ni], acc[mi][ni], 0, 0, 0);
        }
    }

    // epilogue; C/D layout: m = quad*4+r, n = cl
    #pragma unroll
    for (int ni = 0; ni < 4; ni++) {
        const int coln = bn + wn + ni * 16 + cl;
        const float bs = bias ? bias[coln] : 0.f;
        #pragma unroll
        for (int mi = 0; mi < 4; mi++) {
            #pragma unroll
            for (int r = 0; r < 4; r++) {
                const int row = bm + wm + mi * 16 + quad * 4 + r;
                const float v = acc[mi][ni][r] + bs;
                if (MODE == 0) {
                    ((unsigned short*)Cout)[(size_t)row * N + coln] = f2bf(v);
                } else if (MODE == 1) {
                    const int h = coln >> 6, d = coln & 63;
                    const int b = row >> 11, s = row & 2047;
                    ((unsigned short*)Cout)[(((size_t)b * NH + h) * HD + d) * S_LEN + s] = f2bf(v);
                } else {
                    ((float*)Cout)[(size_t)row * N + coln] = v;
                }
            }
        }
    }
}

// ---------------------------------------------------------------------------
// MFMA flash attention. Q,K: bf16 [B,S,D]; VT: bf16 [B,H,HD,S] (pre-transposed);
// O: bf16 [B,S,D]. Fixed-shift softmax (no running max), l reduced at end.
// Grid (S/64, NH, BATCH), 256 threads = 4 waves, 16 q-rows per wave.
// ---------------------------------------------------------------------------
#define TQB 64
#define TKB 64
#define KP  72   // padded stride (bf16): 144 B rows -> 2-way conflicts max

__global__ __launch_bounds__(256) void attn_mfma(
    const unsigned short* __restrict__ Q, const unsigned short* __restrict__ K,
    const unsigned short* __restrict__ VT, const float* __restrict__ pos_bias,
    unsigned short* __restrict__ O)
{
    const int qt = blockIdx.x, h = blockIdx.y, b = blockIdx.z;
    const int tid  = threadIdx.x;
    const int wave = tid >> 6, lane = tid & 63;
    const int quad = lane >> 4, col = lane & 15;
    const int qbase = qt * TQB;
    const int qw = qbase + wave * 16;

    __shared__ __align__(16) unsigned short Ks[TKB][KP];   // [key][d]
    __shared__ __align__(16) unsigned short Vt[HD][KP];    // [d][key]
    __shared__ __align__(16) unsigned short Ps[4][16][KP]; // per-wave P
    __shared__ float bias_s[128];

    bf16x8 qf[2];
    {
        const unsigned short* qp =
            &Q[((size_t)(b * S_LEN) + qw + col) * D_MODEL + h * HD + quad * 8];
        qf[0] = *(const bf16x8*)qp;
        qf[1] = *(const bf16x8*)(qp + 32);
    }

    f32x4 accO[4];
    float l_r[4] = {0.f, 0.f, 0.f, 0.f};
    #pragma unroll
    for (int nb = 0; nb < 4; nb++)
        #pragma unroll
        for (int r = 0; r < 4; r++) accO[nb][r] = 0.f;

    const int skey = tid & 63;
    const int sd   = (tid >> 6) * 16;
    const size_t vbase = ((size_t)(b * NH + h) * HD) * S_LEN;

    for (int kb = 0; kb < S_LEN; kb += TKB) {
        __syncthreads();
        {
            const size_t rowbase = ((size_t)(b * S_LEN) + kb + skey) * D_MODEL + h * HD + sd;
            *(uint4*)&Ks[skey][sd]     = *(const uint4*)&K[rowbase];
            *(uint4*)&Ks[skey][sd + 8] = *(const uint4*)&K[rowbase + 8];
        }
        #pragma unroll
        for (int i = 0; i < 2; i++) {   // V^T tile: 64 d-rows x 64 keys
            const int c = tid + i * 256;
            const int dr = c >> 3, co = (c & 7) * 8;
            *(uint4*)&Vt[dr][co] = *(const uint4*)&VT[vbase + (size_t)dr * S_LEN + kb + co];
        }
        if (tid < 127) {
            int rel = qbase - kb + tid - 63;
            rel = min(max(rel, -(MAXD - 1)), MAXD - 1);
            bias_s[tid] = BIAS_SCALE * pos_bias[(size_t)(rel + MAXD - 1) * NH + h];
        }
        __syncthreads();

        // QK^T: C[q=quad*4+r][key=nb*16+col]
        f32x4 accS[4];
        #pragma unroll
        for (int nb = 0; nb < 4; nb++)
            #pragma unroll
            for (int r = 0; r < 4; r++) accS[nb][r] = 0.f;
        #pragma unroll
        for (int kk = 0; kk < 2; kk++)
            #pragma unroll
            for (int nb = 0; nb < 4; nb++) {
                const bf16x8 kf = *(const bf16x8*)&Ks[nb * 16 + col][kk * 32 + quad * 8];
                accS[nb] = __builtin_amdgcn_mfma_f32_16x16x32_bf16(qf[kk], kf, accS[nb], 0, 0, 0);
            }

        // fixed-shift softmax: p = exp(logit - FIXM); per-lane partial l
        #pragma unroll
        for (int r = 0; r < 4; r++) {
            const int qoff = wave * 16 + quad * 4 + r + 63 - col;
            #pragma unroll
            for (int nb = 0; nb < 4; nb++) {
                const float lg = accS[nb][r] * SCORE_SCALE + bias_s[qoff - nb * 16];
                const float p = __expf(lg - FIXM);
                l_r[r] += p;
                Ps[wave][quad * 4 + r][nb * 16 + col] = f2bf(p);
            }
        }

        // PV: O[q][d=nb*16+col] += P[q][key] * V[key][d]
        #pragma unroll
        for (int kk = 0; kk < 2; kk++) {
            const bf16x8 af = *(const bf16x8*)&Ps[wave][col][kk * 32 + quad * 8];
            #pragma unroll
            for (int nb = 0; nb < 4; nb++) {
                const bf16x8 vf = *(const bf16x8*)&Vt[nb * 16 + col][kk * 32 + quad * 8];
                accO[nb] = __builtin_amdgcn_mfma_f32_16x16x32_bf16(af, vf, accO[nb], 0, 0, 0);
            }
        }
    }

    // reduce l across the 16-lane row group, store bf16
    #pragma unroll
    for (int r = 0; r < 4; r++) {
        float l = l_r[r];
        #pragma unroll
        for (int s = 1; s < 16; s <<= 1) l += __shfl_xor(l, s);
        const float inv = 1.0f / l;
        const size_t row = (size_t)(b * S_LEN) + qw + quad * 4 + r;
        #pragma unroll
        for (int nb = 0; nb < 4; nb++)
            O[row * D_MODEL + h * HD + nb * 16 + col] = f2bf(accO[nb][r] * inv);
    }
}

// ---------------------------------------------------------------------------
extern "C" void kernel_launch(void* const* d_in, const int* in_sizes, int n_in,
                              void* d_out, int out_size, void* d_ws, size_t ws_size,
                              hipStream_t stream)
{
    const float* x        = (const float*)d_in[0];
    const float* Wq       = (const float*)d_in[1];
    const float* bq       = (const float*)d_in[2];
    const float* Wk       = (const float*)d_in[3];
    const float* Wv       = (const float*)d_in[4];
    const float* bv       = (const float*)d_in[5];
    const float* Wo       = (const float*)d_in[6];
    const float* bo       = (const float*)d_in[7];
    const float* pos_bias = (const float*)d_in[8];
    float* out = (float*)d_out;

    const size_t ELEMS = (size_t)BATCH * S_LEN * D_MODEL;  // 4 Mi
    const size_t WELEMS = (size_t)D_MODEL * D_MODEL;       // 1 Mi
    unsigned short* xb     = (unsigned short*)d_ws;
    unsigned short* Wqt    = xb + ELEMS;
    unsigned short* Wkt    = Wqt + WELEMS;
    unsigned short* Wvt    = Wkt + WELEMS;
    unsigned short* Wot_hi = Wvt + WELEMS;
    unsigned short* Wot_lo = Wot_hi + WELEMS;
    unsigned short* Qb     = Wot_lo + WELEMS;
    unsigned short* Kb     = Qb + ELEMS;
    unsigned short* VTb    = Kb + ELEMS;   // [B,H,HD,S]
    unsigned short* Ab     = VTb + ELEMS;  // attention output bf16 [B,S,D]

    const int M = BATCH * S_LEN;  // 4096

    cvt_bf16<<<ELEMS / (256 * 8), 256, 0, stream>>>(x, xb);
    dim3 tgrid(32, 32);
    wt_convert<<<tgrid, 256, 0, stream>>>(Wq, Wqt, nullptr);
    wt_convert<<<tgrid, 256, 0, stream>>>(Wk, Wkt, nullptr);
    wt_convert<<<tgrid, 256, 0, stream>>>(Wv, Wvt, nullptr);
    wt_convert<<<tgrid, 256, 0, stream>>>(Wo, Wot_hi, Wot_lo);

    dim3 ggrid(D_MODEL / GBN, M / GBM);  // (8, 32)
    gemm_mfma<0, false><<<ggrid, 256, 0, stream>>>(xb, Wqt, nullptr, bq, Qb,  M, D_MODEL, D_MODEL);
    gemm_mfma<0, false><<<ggrid, 256, 0, stream>>>(xb, Wkt, nullptr, nullptr, Kb, M, D_MODEL, D_MODEL);
    gemm_mfma<1, false><<<ggrid, 256, 0, stream>>>(xb, Wvt, nullptr, bv, VTb, M, D_MODEL, D_MODEL);

    attn_mfma<<<dim3(S_LEN / TQB, NH, BATCH), 256, 0, stream>>>(Qb, Kb, VTb, pos_bias, Ab);

    gemm_mfma<2, true><<<ggrid, 256, 0, stream>>>(Ab, Wot_hi, Wot_lo, bo, out, M, D_MODEL, D_MODEL);
}

// Round 4
// 249.815 us; speedup vs baseline: 15.5693x; 1.2251x over previous
//
#include <hip/hip_runtime.h>
#include <hip/hip_bf16.h>
#include <cstddef>
#include <cstdint>

// Problem constants (fixed by reference)
#define BATCH   2
#define S_LEN   2048
#define D_MODEL 1024
#define NH      16
#define HD      64
#define MAXD    1024

// logits = scores*(1/sqrt(64)) + (scores + rel_bias)*64^-0.25
//        = scores*0.47855339 + rel_bias*0.35355339
#define SCORE_SCALE 0.47855339059327373f
#define BIAS_SCALE  0.35355339059327373f
// fixed softmax shift (|logit| << 8): softmax is shift-invariant; folded into bias table
#define FIXM 8.0f

typedef __attribute__((ext_vector_type(8))) short bf16x8;
typedef __attribute__((ext_vector_type(4))) float f32x4;

static __device__ __forceinline__ unsigned short f2bf(float f) {
    __hip_bfloat16 h = __float2bfloat16(f);
    return *reinterpret_cast<unsigned short*>(&h);
}
static __device__ __forceinline__ float bf2f(unsigned short u) {
    union { unsigned int i; float f; } c;
    c.i = ((unsigned int)u) << 16;
    return c.f;
}

#define GLDS(gp, lp) __builtin_amdgcn_global_load_lds( \
    (const __attribute__((address_space(1))) void*)(gp), \
    (__attribute__((address_space(3))) void*)(lp), 16, 0, 0)

// ---------------------------------------------------------------------------
// fp32 -> bf16 elementwise convert (x).
// ---------------------------------------------------------------------------
__global__ __launch_bounds__(256) void cvt_bf16(
    const float* __restrict__ src, unsigned short* __restrict__ dst)
{
    const size_t i = ((size_t)blockIdx.x * 256 + threadIdx.x) * 8;
    const float4 a = *(const float4*)(src + i);
    const float4 b = *(const float4*)(src + i + 4);
    unsigned short u[8] = {f2bf(a.x), f2bf(a.y), f2bf(a.z), f2bf(a.w),
                           f2bf(b.x), f2bf(b.y), f2bf(b.z), f2bf(b.w)};
    *(uint4*)(dst + i) = *(const uint4*)u;
}

// ---------------------------------------------------------------------------
// All weight transposes+converts in one launch. z=0,1,2 -> Wq/Wk/Wv into the
// concatenated Wqkvt [3072][1024]; z=3 -> Wo split-precision hi/lo.
// ---------------------------------------------------------------------------
__global__ __launch_bounds__(256) void wt_convert_all(
    const float* __restrict__ Wq, const float* __restrict__ Wk,
    const float* __restrict__ Wv, const float* __restrict__ Wo,
    unsigned short* __restrict__ Wqkvt, unsigned short* __restrict__ Wot_hi,
    unsigned short* __restrict__ Wot_lo)
{
    const int z = blockIdx.z;
    const float* W = (z == 0) ? Wq : (z == 1) ? Wk : (z == 2) ? Wv : Wo;
    unsigned short* hi = (z < 3) ? Wqkvt + (size_t)z * 1024 * 1024 : Wot_hi;
    unsigned short* lo = (z == 3) ? Wot_lo : nullptr;

    __shared__ float t[32][33];
    const int bx = blockIdx.x * 32, by = blockIdx.y * 32;
    const int tx = threadIdx.x & 31, ty = threadIdx.x >> 5;  // ty 0..7
    #pragma unroll
    for (int i = 0; i < 4; i++)
        t[ty + 8 * i][tx] = W[(size_t)(by + ty + 8 * i) * 1024 + bx + tx];
    __syncthreads();
    #pragma unroll
    for (int i = 0; i < 4; i++) {
        const float v = t[tx][ty + 8 * i];       // = W[by+tx][bx+ty+8i]
        const unsigned short h = f2bf(v);
        const size_t o = (size_t)(bx + ty + 8 * i) * 1024 + by + tx;
        hi[o] = h;
        if (lo) lo[o] = f2bf(v - bf2f(h));
    }
}

// ---------------------------------------------------------------------------
// bf16 MFMA GEMM: C[M,N] = A[M,K] @ Bt[N,K]^T (+bias).
// 128x128 tile, BK=32, 256 threads = 4 waves (2x2), 4x4 16x16x32 frags/wave.
// MODE 2: fp32 C [M,N] (final projection).
// MODE 3: fused QKV epilogue. Cout is base of {Qb | Kb | VTb} each 4Mi bf16;
//         col region 0->Q [B,S,D], 1->K [B,S,D], 2->V^T [B,H,HD,S] (packed).
// SPLITB: accumulate A@Bt + A@Bt2 (split-precision weight).
// ---------------------------------------------------------------------------
#define GBM 128
#define GBN 128
#define GBK 32

template<int MODE, bool SPLITB>
__global__ __launch_bounds__(256) void gemm_mfma(
    const unsigned short* __restrict__ A, const unsigned short* __restrict__ Bt,
    const unsigned short* __restrict__ Bt2, const float* __restrict__ bias,
    const float* __restrict__ bias2, void* __restrict__ Cout,
    int M, int N, int K)
{
    __shared__ __align__(16) unsigned short As[GBM][GBK];
    __shared__ __align__(16) unsigned short Bs[SPLITB ? 2 : 1][GBN][GBK];

    const int tid = threadIdx.x;
    const int wave = tid >> 6, lane = tid & 63;
    const int quad = lane >> 4, cl = lane & 15;
    const int wm = (wave & 1) * 64, wn = (wave >> 1) * 64;
    const int bm = blockIdx.y * GBM, bn = blockIdx.x * GBN;

    const int sr = wave * 32 + (lane >> 2);   // staging row (second instr: +16)
    const int sc = (lane & 3) * 8;            // 16 B chunk
    const unsigned short* aS0 = A   + (size_t)(bm + sr) * K + sc;
    const unsigned short* aS1 = aS0 + (size_t)16 * K;
    const unsigned short* bS0 = Bt  + (size_t)(bn + sr) * K + sc;
    const unsigned short* bS1 = bS0 + (size_t)16 * K;
    const unsigned short* cS0 = SPLITB ? Bt2 + (size_t)(bn + sr) * K + sc : nullptr;
    const unsigned short* cS1 = SPLITB ? cS0 + (size_t)16 * K : nullptr;
    unsigned short* aD0 = &As[wave * 32][0];
    unsigned short* aD1 = &As[wave * 32 + 16][0];
    unsigned short* bD0 = &Bs[0][wave * 32][0];
    unsigned short* bD1 = &Bs[0][wave * 32 + 16][0];
    unsigned short* cD0 = SPLITB ? &Bs[1][wave * 32][0] : nullptr;
    unsigned short* cD1 = SPLITB ? &Bs[1][wave * 32 + 16][0] : nullptr;

    f32x4 acc[4][4];
    #pragma unroll
    for (int mi = 0; mi < 4; mi++)
        #pragma unroll
        for (int ni = 0; ni < 4; ni++)
            #pragma unroll
            for (int r = 0; r < 4; r++) acc[mi][ni][r] = 0.f;

    for (int k0 = 0; k0 < K; k0 += GBK) {
        __syncthreads();
        GLDS(aS0, aD0); GLDS(aS1, aD1);
        GLDS(bS0, bD0); GLDS(bS1, bD1);
        if (SPLITB) { GLDS(cS0, cD0); GLDS(cS1, cD1); }
        aS0 += GBK; aS1 += GBK; bS0 += GBK; bS1 += GBK;
        if (SPLITB) { cS0 += GBK; cS1 += GBK; }
        __syncthreads();  // barrier drains vmcnt -> glds data visible

        bf16x8 af[4], bf[4];
        #pragma unroll
        for (int mi = 0; mi < 4; mi++)
            af[mi] = *(const bf16x8*)&As[wm + mi * 16 + cl][quad * 8];
        #pragma unroll
        for (int ni = 0; ni < 4; ni++)
            bf[ni] = *(const bf16x8*)&Bs[0][wn + ni * 16 + cl][quad * 8];
        #pragma unroll
        for (int mi = 0; mi < 4; mi++)
            #pragma unroll
            for (int ni = 0; ni < 4; ni++)
                acc[mi][ni] = __builtin_amdgcn_mfma_f32_16x16x32_bf16(
                    af[mi], bf[ni], acc[mi][ni], 0, 0, 0);
        if (SPLITB) {
            bf16x8 bf2[4];
            #pragma unroll
            for (int ni = 0; ni < 4; ni++)
                bf2[ni] = *(const bf16x8*)&Bs[1][wn + ni * 16 + cl][quad * 8];
            #pragma unroll
            for (int mi = 0; mi < 4; mi++)
                #pragma unroll
                for (int ni = 0; ni < 4; ni++)
                    acc[mi][ni] = __builtin_amdgcn_mfma_f32_16x16x32_bf16(
                        af[mi], bf2[ni], acc[mi][ni], 0, 0, 0);
        }
    }

    // epilogue; C/D layout: m = quad*4+r, n = cl
    #pragma unroll
    for (int ni = 0; ni < 4; ni++) {
        const int coln = bn + wn + ni * 16 + cl;
        float bs = 0.f;
        int region = 0, c = coln;
        if (MODE == 3) {
            region = coln >> 10; c = coln & 1023;
            bs = (region == 0) ? bias[c] : (region == 2) ? bias2[c] : 0.f;
        } else {
            bs = bias ? bias[coln] : 0.f;
        }
        #pragma unroll
        for (int mi = 0; mi < 4; mi++) {
            const int row0 = bm + wm + mi * 16 + quad * 4;
            if (MODE == 3 && region == 2) {
                // V^T store: pack 4 consecutive s (r=0..3) into one b64
                const int hh = c >> 6, d = c & 63;
                const int bb = row0 >> 11, s0 = row0 & 2047;
                unsigned short u[4];
                #pragma unroll
                for (int r = 0; r < 4; r++) u[r] = f2bf(acc[mi][ni][r] + bs);
                unsigned short* dst = (unsigned short*)Cout + (size_t)8 * 1024 * 1024
                    + (((size_t)bb * NH + hh) * HD + d) * S_LEN + s0;
                *(uint2*)dst = *(const uint2*)u;
            } else {
                #pragma unroll
                for (int r = 0; r < 4; r++) {
                    const int row = row0 + r;
                    const float v = acc[mi][ni][r] + bs;
                    if (MODE == 3) {
                        unsigned short* dst = (unsigned short*)Cout
                            + (size_t)region * 4 * 1024 * 1024;
                        dst[(size_t)row * 1024 + c] = f2bf(v);
                    } else {
                        ((float*)Cout)[(size_t)row * N + coln] = v;
                    }
                }
            }
        }
    }
}

// ---------------------------------------------------------------------------
// MFMA flash attention, transposed-score formulation.
// Q,K: bf16 [B,S,D]; VT: bf16 [B,H,HD,S]; O: bf16 [B,S,D].
// S^T = mfma(K-frag, Q-frag): C[key=quad*4+r][q=col] -> one lane holds 4
// consecutive keys for a fixed q => packed b64 P-writes, scalar l per lane.
// Fixed-shift softmax (FIXM folded into bias table), l reduced once at end.
// ---------------------------------------------------------------------------
#define TQB 64
#define TKB 64
#define KP  72   // padded stride (bf16): 144 B rows -> 2-way conflicts max

__global__ __launch_bounds__(256) void attn_mfma(
    const unsigned short* __restrict__ Q, const unsigned short* __restrict__ K,
    const unsigned short* __restrict__ VT, const float* __restrict__ pos_bias,
    unsigned short* __restrict__ O)
{
    const int qt = blockIdx.x, h = blockIdx.y, b = blockIdx.z;
    const int tid  = threadIdx.x;
    const int wave = tid >> 6, lane = tid & 63;
    const int quad = lane >> 4, col = lane & 15;
    const int qbase = qt * TQB;
    const int qw = qbase + wave * 16;

    __shared__ __align__(16) unsigned short Ks[TKB][KP];   // [key][d]
    __shared__ __align__(16) unsigned short Vt[HD][KP];    // [d][key]
    __shared__ __align__(16) unsigned short Ps[4][16][KP]; // per-wave P [q][key]
    __shared__ float bias_s[128];

    bf16x8 qf[2];
    {
        const unsigned short* qp =
            &Q[((size_t)(b * S_LEN) + qw + col) * D_MODEL + h * HD + quad * 8];
        qf[0] = *(const bf16x8*)qp;
        qf[1] = *(const bf16x8*)(qp + 32);
    }

    f32x4 accO[4];
    float lsum = 0.f;   // one accumulator: all 16 scores/lane/tile share q=col
    #pragma unroll
    for (int nb = 0; nb < 4; nb++)
        #pragma unroll
        for (int r = 0; r < 4; r++) accO[nb][r] = 0.f;

    const int skey = tid & 63;
    const int sd   = (tid >> 6) * 16;
    const size_t vbase = ((size_t)(b * NH + h) * HD) * S_LEN;
    const int tb0 = wave * 16 + col + 63 - quad * 4;  // bias idx base (tile-inv)

    for (int kb = 0; kb < S_LEN; kb += TKB) {
        __syncthreads();
        {
            const size_t rowbase = ((size_t)(b * S_LEN) + kb + skey) * D_MODEL + h * HD + sd;
            *(uint4*)&Ks[skey][sd]     = *(const uint4*)&K[rowbase];
            *(uint4*)&Ks[skey][sd + 8] = *(const uint4*)&K[rowbase + 8];
        }
        #pragma unroll
        for (int i = 0; i < 2; i++) {   // V^T tile: 64 d-rows x 64 keys
            const int c = tid + i * 256;
            const int dr = c >> 3, co = (c & 7) * 8;
            *(uint4*)&Vt[dr][co] = *(const uint4*)&VT[vbase + (size_t)dr * S_LEN + kb + co];
        }
        if (tid < 127) {
            int rel = qbase - kb + tid - 63;
            rel = min(max(rel, -(MAXD - 1)), MAXD - 1);
            bias_s[tid] = BIAS_SCALE * pos_bias[(size_t)(rel + MAXD - 1) * NH + h] - FIXM;
        }
        __syncthreads();

        // S^T: C[key = nb*16 + quad*4 + r][q = col]
        f32x4 accS[4];
        #pragma unroll
        for (int nb = 0; nb < 4; nb++)
            #pragma unroll
            for (int r = 0; r < 4; r++) accS[nb][r] = 0.f;
        #pragma unroll
        for (int kk = 0; kk < 2; kk++)
            #pragma unroll
            for (int nb = 0; nb < 4; nb++) {
                const bf16x8 kf = *(const bf16x8*)&Ks[nb * 16 + col][kk * 32 + quad * 8];
                accS[nb] = __builtin_amdgcn_mfma_f32_16x16x32_bf16(kf, qf[kk], accS[nb], 0, 0, 0);
            }

        // softmax: p = exp(score*SC + bias - FIXM); packed b64 P-writes
        #pragma unroll
        for (int nb = 0; nb < 4; nb++) {
            const int tb = tb0 - nb * 16;
            float p[4];
            #pragma unroll
            for (int r = 0; r < 4; r++) {
                const float lg = fmaf(accS[nb][r], SCORE_SCALE, bias_s[tb - r]);
                p[r] = __expf(lg);
                lsum += p[r];
            }
            const __hip_bfloat162 h0 = __float22bfloat162_rn(make_float2(p[0], p[1]));
            const __hip_bfloat162 h1 = __float22bfloat162_rn(make_float2(p[2], p[3]));
            uint2 w;
            w.x = *(const unsigned int*)&h0;
            w.y = *(const unsigned int*)&h1;
            *(uint2*)&Ps[wave][col][nb * 16 + quad * 4] = w;
        }

        // PV: O[q=quad*4+r][d=nb*16+col] += P[q][key] * V[key][d]
        #pragma unroll
        for (int kk = 0; kk < 2; kk++) {
            const bf16x8 af = *(const bf16x8*)&Ps[wave][col][kk * 32 + quad * 8];
            #pragma unroll
            for (int nb = 0; nb < 4; nb++) {
                const bf16x8 vf = *(const bf16x8*)&Vt[nb * 16 + col][kk * 32 + quad * 8];
                accO[nb] = __builtin_amdgcn_mfma_f32_16x16x32_bf16(af, vf, accO[nb], 0, 0, 0);
            }
        }
    }

    // reduce l (lanes col, col+16, col+32, col+48 share q=col), redistribute
    lsum += __shfl_xor(lsum, 16);
    lsum += __shfl_xor(lsum, 32);
    #pragma unroll
    for (int r = 0; r < 4; r++) {
        const float inv = 1.0f / __shfl(lsum, quad * 4 + r);
        const size_t row = (size_t)(b * S_LEN) + qw + quad * 4 + r;
        #pragma unroll
        for (int nb = 0; nb < 4; nb++)
            O[row * D_MODEL + h * HD + nb * 16 + col] = f2bf(accO[nb][r] * inv);
    }
}

// ---------------------------------------------------------------------------
extern "C" void kernel_launch(void* const* d_in, const int* in_sizes, int n_in,
                              void* d_out, int out_size, void* d_ws, size_t ws_size,
                              hipStream_t stream)
{
    const float* x        = (const float*)d_in[0];
    const float* Wq       = (const float*)d_in[1];
    const float* bq       = (const float*)d_in[2];
    const float* Wk       = (const float*)d_in[3];
    const float* Wv       = (const float*)d_in[4];
    const float* bv       = (const float*)d_in[5];
    const float* Wo       = (const float*)d_in[6];
    const float* bo       = (const float*)d_in[7];
    const float* pos_bias = (const float*)d_in[8];
    float* out = (float*)d_out;

    const size_t ELEMS  = (size_t)BATCH * S_LEN * D_MODEL;  // 4 Mi
    const size_t WELEMS = (size_t)D_MODEL * D_MODEL;        // 1 Mi
    unsigned short* xb     = (unsigned short*)d_ws;
    unsigned short* Wqkvt  = xb + ELEMS;                    // [3072][1024]
    unsigned short* Wot_hi = Wqkvt + 3 * WELEMS;
    unsigned short* Wot_lo = Wot_hi + WELEMS;
    unsigned short* QKV    = Wot_lo + WELEMS;               // Qb | Kb | VTb
    unsigned short* Qb     = QKV;
    unsigned short* Kb     = Qb + ELEMS;
    unsigned short* VTb    = Kb + ELEMS;                    // [B,H,HD,S]
    unsigned short* Ab     = VTb + ELEMS;                   // attn out bf16 [B,S,D]

    const int M = BATCH * S_LEN;  // 4096

    cvt_bf16<<<ELEMS / (256 * 8), 256, 0, stream>>>(x, xb);
    wt_convert_all<<<dim3(32, 32, 4), 256, 0, stream>>>(
        Wq, Wk, Wv, Wo, Wqkvt, Wot_hi, Wot_lo);

    // fused QKV projection: N = 3072
    gemm_mfma<3, false><<<dim3(3072 / GBN, M / GBM), 256, 0, stream>>>(
        xb, Wqkvt, nullptr, bq, bv, QKV, M, 3072, D_MODEL);

    attn_mfma<<<dim3(S_LEN / TQB, NH, BATCH), 256, 0, stream>>>(Qb, Kb, VTb, pos_bias, Ab);

    gemm_mfma<2, true><<<dim3(D_MODEL / GBN, M / GBM), 256, 0, stream>>>(
        Ab, Wot_hi, Wot_lo, bo, nullptr, out, M, D_MODEL, D_MODEL);
}